// Round 18
// baseline (195.035 us; speedup 1.0000x reference)
//
#include <hip/hip_runtime.h>
#include <hip/hip_bf16.h>
#include <math.h>

// Problem constants (fixed by the reference)
#define Bn   2
#define Sn   2048
#define En   1024
#define Hn   16
#define DKn  64
#define Mn   (Bn * Sn)   // 4096
#define NELT ((size_t)Mn * En)   // 4,194,304
#define WELT ((size_t)En * En)   // 1,048,576
#define HELT (Sn * DKn)          // 131072 elems per head (K/V frag regions)

// Q pre-scale: 1/sqrt(DK) * log2(e)  -> attention uses exp2 (raw v_exp_f32)
#define QSCALE 0.18033688011112042f

typedef __attribute__((ext_vector_type(8))) short     short8;   // 8x16b
typedef __attribute__((ext_vector_type(8))) _Float16  half8;    // 8 f16
typedef __attribute__((ext_vector_type(4))) _Float16  half4;
typedef __attribute__((ext_vector_type(2))) __fp16    fp16x2;   // cvt_pkrtz ret
typedef __attribute__((ext_vector_type(4))) float     float4v;  // MFMA C/D

static __device__ __forceinline__ unsigned short f2h(float f) {
    _Float16 h = (_Float16)f;
    return *reinterpret_cast<unsigned short*>(&h);
}

static __device__ __forceinline__ float fexp2(float x) {
#if __has_builtin(__builtin_amdgcn_exp2f)
    return __builtin_amdgcn_exp2f(x);
#else
    return exp2f(x);
#endif
}

// A/B-fragment-major offset for a [rows][1024] f16 matrix staged as 16x32
// tiles: off = ((row>>4)*32 + (k>>5))*512 + (((k>>3)&3)*16 + (row&15))*8 + (k&7)
static __device__ __forceinline__ size_t fragoff(int row, int k) {
    return ((size_t)((row >> 4) * 32 + (k >> 5))) * 512
         + (size_t)((((k >> 3) & 3) * 16 + (row & 15)) * 8 + (k & 7));
}

// async global->LDS, 16B/lane; LDS dst = wave-uniform base + lane*16
#define GLL16(gp, lp) __builtin_amdgcn_global_load_lds(                      \
    (const __attribute__((address_space(1))) void*)(gp),                     \
    (__attribute__((address_space(3))) void*)(lp), 16, 0, 0)

// counted vmem wait (never 0 in steady state) + raw barrier + sched fence.
// Per-wave vmcnt + identical issue pattern across waves => after barrier,
// ALL waves' tile-t loads are complete. (R3-proven for gemm_s; R18: applied
// to the lean attn structure which now matches gemm_s's NW=4 shape.)
#define PIPE_WAIT_BARRIER(N)                                                 \
    do {                                                                     \
        asm volatile("s_waitcnt vmcnt(%0)" :: "i"(N) : "memory");            \
        __builtin_amdgcn_s_barrier();                                        \
        __builtin_amdgcn_sched_barrier(0);                                   \
    } while (0)

// ---------------------------------------------------------------------------
// Fused converter: blocks [0,4096) = x fp32 -> f16 A-frag-major;
// blocks [4096,8192) = W^T B-frag-major transpose (one launch, R17).
// ---------------------------------------------------------------------------
__global__ __launch_bounds__(256) void conv_fused(
    const float* __restrict__ in, _Float16* __restrict__ out,
    const float* __restrict__ W0, const float* __restrict__ W1,
    const float* __restrict__ W2, const float* __restrict__ W3,
    _Float16* __restrict__ Wt4)
{
    __shared__ float sT[32][33];
    if (blockIdx.x < 4096) {
        // conv_a path
        const int i = (blockIdx.x * 256 + threadIdx.x) * 4;
        float4 v = *(const float4*)&in[i];
        const int m = i >> 10, k = i & 1023;  // k%4==0 -> half4 stays in octet
        half4 h = { (_Float16)v.x, (_Float16)v.y, (_Float16)v.z, (_Float16)v.w };
        *(half4*)&out[fragoff(m, k)] = h;
    } else {
        // conv_wt4 path
        const int r0 = blockIdx.x - 4096;
        const int z  = r0 >> 10, rem = r0 & 1023;
        const int n0 = (rem & 31) * 32, k0 = (rem >> 5) * 32;
        const float* W = (z == 0) ? W0 : (z == 1) ? W1 : (z == 2) ? W2 : W3;
        _Float16* Wt = Wt4 + (size_t)z * WELT;

        const int t = threadIdx.x;
        #pragma unroll
        for (int it = 0; it < 4; ++it) {
            const int idx = t + 256 * it;
            const int r = idx >> 5, cl = idx & 31;
            sT[r][cl] = W[(size_t)(k0 + r) * En + n0 + cl];
        }
        __syncthreads();
        #pragma unroll
        for (int it = 0; it < 4; ++it) {
            const int idx = t + 256 * it;
            const int r = idx >> 5, cl = idx & 31;
            // element W^T[n0+r][k0+cl]
            Wt[fragoff(n0 + r, k0 + cl)] = (_Float16)sT[cl][r];
        }
    }
}

// ---------------------------------------------------------------------------
// fp16 MFMA GEMM, fragment-major LDS, 3-buffer 2-tile-deep pipeline (R3).
// A and B stored frag-major in global: each GLL16 source is
// base + frag*512 + lane*8 — fully-coalesced 1KB wave read (R8 win).
// Block tile: (MT*16) x 128, 4 waves (2x2), wave = (MT*8) x 64.
// MODE 0: fp32 out[M][1024] (O projection, bias b0)
// MODE 1: fused QKV (Ntot=3072): Q row-major f16 (scaled QSCALE);
//         K attn-frag-major; V^T attn-frag-major with PERMUTED-k layout
//         (lane (p,c) holds its 8 PV keys contiguously -> b128 read and
//          K=32 PV MFMA; permutation kappa(p,j) = (j>>2)*16 + p*4 + (j&3)).
// ---------------------------------------------------------------------------
template<int MT, int MODE>
__global__ __launch_bounds__(256) void gemm_s(
    const _Float16* __restrict__ A, const _Float16* __restrict__ Bt,
    const float* __restrict__ b0, const float* __restrict__ b1,
    const float* __restrict__ b2, void* __restrict__ out, int nT)
{
    constexpr int MH = MT / 2;        // m-frags per wave
    constexpr int NF = MT + 8;        // total frags to stage
    constexpr int NW = NF / 4;        // frags staged per wave (= loads/tile/wave)
    constexpr int BUFE = NF * 512;    // fp16 elems per LDS buffer
    constexpr int NT = En / 32;       // 32 K-tiles

    __shared__ _Float16 sAB[3 * BUFE];

    const int tid  = threadIdx.x;
    const int wid  = tid >> 6, lane = tid & 63;
    const int c    = lane & 15, p = lane >> 4;

    // XCD-aware decode (heuristic: block -> XCD is round-robin by linear id)
    const int lin  = blockIdx.x;
    const int xcd  = lin & 7, slot = lin >> 3;
    const int slab = nT >> 3;                     // n-tiles per XCD
    const int n_t  = xcd * slab + (slot % slab);
    const int m_t  = slot / slab;
    const int m0   = m_t * (MT * 16), n0 = n_t * 128;

    // staging: frag fi in [0,MT) = A-frag, [MT,MT+8) = B-frag; sources are
    // frag-major: (group)*32*512 + t*512 + lane*8, t = K-step index
    const _Float16* gsrc[NW];
    _Float16* ldst[NW];
    #pragma unroll
    for (int j = 0; j < NW; ++j) {
        const int fi = wid * NW + j;
        if (fi < MT) {
            gsrc[j] = A + ((size_t)(m0 / 16 + fi) * 32) * 512 + lane * 8;
        } else {
            const int z = n0 >> 10, nn0 = n0 & 1023;
            gsrc[j] = Bt + (size_t)z * WELT
                    + ((size_t)(nn0 / 16 + (fi - MT)) * 32) * 512 + lane * 8;
        }
        ldst[j] = &sAB[fi * 512];
    }

    const int mf = (wid >> 1) * MH;    // wave's first m-frag
    const int nf = (wid & 1) * 4;      // wave's first n-frag

    float4v acc[MH][4];
    #pragma unroll
    for (int mt = 0; mt < MH; ++mt)
        #pragma unroll
        for (int nt = 0; nt < 4; ++nt)
            acc[mt][nt] = (float4v){0.f, 0.f, 0.f, 0.f};

    auto compute = [&](const _Float16* sb) {
        half8 av[MH], bv[4];
        #pragma unroll
        for (int mt = 0; mt < MH; ++mt)
            av[mt] = *(const half8*)&sb[(mf + mt) * 512 + lane * 8];
        #pragma unroll
        for (int nt = 0; nt < 4; ++nt)
            bv[nt] = *(const half8*)&sb[(MT + nf + nt) * 512 + lane * 8];
        #pragma unroll
        for (int mt = 0; mt < MH; ++mt)
            #pragma unroll
            for (int nt = 0; nt < 4; ++nt)
                acc[mt][nt] = __builtin_amdgcn_mfma_f32_16x16x32_f16(
                    av[mt], bv[nt], acc[mt][nt], 0, 0, 0);
    };

    // prologue: stage tiles 0 and 1 into buffers 0 and 1
    #pragma unroll
    for (int j = 0; j < NW; ++j)
        GLL16(gsrc[j], ldst[j]);
    #pragma unroll
    for (int j = 0; j < NW; ++j)
        GLL16(gsrc[j] + 512, ldst[j] + BUFE);

    int cur = 0;                        // t % 3
    for (int t = 0; t < NT; ++t) {
        if (t < NT - 1) PIPE_WAIT_BARRIER(NW);
        else            PIPE_WAIT_BARRIER(0);
        if (t + 2 < NT) {               // stage tile t+2 into buf[(t+2)%3]
            int st = cur - 1; if (st < 0) st += 3;   // (t+2)%3 == (t-1)%3
            #pragma unroll
            for (int j = 0; j < NW; ++j)
                GLL16(gsrc[j] + (t + 2) * 512, ldst[j] + st * BUFE);
        }
        compute(&sAB[cur * BUFE]);
        ++cur; if (cur == 3) cur = 0;
    }

    // epilogue (C/D: col=c -> n, row=p*4+r -> m)
    #pragma unroll
    for (int mt = 0; mt < MH; ++mt) {
        #pragma unroll
        for (int nt = 0; nt < 4; ++nt) {
            const int n = n0 + (nf + nt) * 16 + c;
            const int mbase = m0 + (mf + mt) * 16 + p * 4;
            if (MODE == 0) {
                const float bia = b0[n];
                float* o = (float*)out;
                #pragma unroll
                for (int r = 0; r < 4; ++r)
                    o[(size_t)(mbase + r) * En + n] = acc[mt][nt][r] + bia;
            } else {
                const int which = n >> 10, nn = n & 1023;
                const int hh = nn >> 6, d = nn & 63;
                const float* bb = (which == 0) ? b0 : (which == 1) ? b1 : b2;
                const float bia = bb[nn];
                unsigned short* o = (unsigned short*)out + (size_t)which * NELT;
                if (which == 0) {          // Q row-major [b,h,s,d], scaled
                    #pragma unroll
                    for (int r = 0; r < 4; ++r) {
                        const int m = mbase + r;
                        const int b = m >> 11, s = m & 2047;
                        o[(((size_t)(b * Hn + hh) * Sn + s) << 6) + d] =
                            f2h((acc[mt][nt][r] + bia) * QSCALE);
                    }
                } else if (which == 1) {   // K attn-frag-major per head
                    #pragma unroll
                    for (int r = 0; r < 4; ++r) {
                        const int m = mbase + r;
                        const int b = m >> 11, s = m & 2047;
                        const int T = s >> 7, sk = s & 127;
                        const int f = ((sk >> 4) << 1) + (d >> 5);
                        const int l = (((d >> 3) & 3) << 4) + (sk & 15);
                        o[(size_t)(b * Hn + hh) * HELT + T * 8192
                          + f * 512 + l * 8 + (d & 7)] =
                            f2h(acc[mt][nt][r] + bia);
                    }
                } else {                   // V^T attn-frag-major, permuted-k
                    const int b = mbase >> 11, sv = mbase & 2047;
                    const int T = sv >> 7, kk = sv & 127;
                    const int kk32 = kk & 31;
                    const int f = ((d >> 4) << 2) + (kk >> 5);
                    // elem = (p*16 + (d&15))*8 + hi*4 + j2; r = j2 (kk%4==0)
                    const int el = ((((kk32 >> 2) & 3) * 16 + (d & 15)) << 3)
                                 + ((kk32 >> 4) << 2);
                    ushort4 pk = make_ushort4(
                        f2h(acc[mt][nt][0] + bia), f2h(acc[mt][nt][1] + bia),
                        f2h(acc[mt][nt][2] + bia), f2h(acc[mt][nt][3] + bia));
                    *(ushort4*)&o[(size_t)(b * Hn + hh) * HELT + T * 8192
                                  + f * 512 + el] = pk;
                }
            }
        }
    }
}

// ---------------------------------------------------------------------------
// MFMA flash attention v15 = v14 (R17-passing: v10 data path at q-tile 64 /
// KVBLK 64, ones-MFMA row-sum) with the GEMM's 3-buffer counted-vmcnt
// pipeline replacing the 2-buffer vmcnt(0) drain: iter t waits vmcnt(4)
// [tile t's 4 loads done, t+1's 4 in flight across the barrier], stages t+2,
// computes buf[t%3]. Each load now has ~2 tiles of compute to hide under —
// R17 isolated the per-iter drain as the last structural stall suspect
// (MFMA 31 + VALU 41, ~28% stall; occupancy/conflicts/requests all ruled
// out). R3's attn counted-vmcnt loss was on the old heavy structure; the
// lean kernel now matches gemm_s's NW=4 shape where this measured best.
// LDS 3x(8K+8K) = 48 KB -> 3 blocks/CU (R16: attn occupancy-insensitive).
// ---------------------------------------------------------------------------
__global__ __launch_bounds__(256) void attn_v15(
    const unsigned short* __restrict__ Q, const unsigned short* __restrict__ K,
    const unsigned short* __restrict__ Vt, _Float16* __restrict__ ctx)
{
    constexpr int TBE = 8 * 512;                  // elems per tile buffer (8 KB)
    constexpr int NT  = Sn / 64;                  // 32 key-chunks
    __shared__ unsigned short sK[3 * TBE];        // 24 KB
    __shared__ unsigned short sV[3 * TBE];        // 24 KB

    const int tid  = threadIdx.x;
    const int wid  = tid >> 6, lane = tid & 63;
    const int c    = lane & 15, p = lane >> 4;

    const int lin  = blockIdx.x;                  // 0..1023
    const int xcd  = lin & 7, slot = lin >> 3;    // slot 0..127
    const int he   = xcd * 4 + (slot & 3);        // 0..31
    const int qt   = slot >> 2;                   // 0..31 (64-row q-tile)
    const int b    = he >> 4, h = he & 15;
    const int q0   = qt * 64 + wid * 16;          // 16 q-rows per wave
    const size_t hb = (size_t)(b * Hn + h);

    const unsigned short* Qh = Q  + hb * Sn * DKn;   // row-major
    const unsigned short* Kh = K  + hb * HELT;       // frag-major tiles
    const unsigned short* Vh = Vt + hb * HELT;       // frag-major (permuted-k)

    // K: chunk is linear at Kh + kt*64; wave stages chunk-frags {2w,2w+1}
    unsigned short* lk[2];
    unsigned short* lv[2];
    #pragma unroll
    for (int j = 0; j < 2; ++j) {
        lk[j] = &sK[(2 * wid + j) * 512];
        lv[j] = &sV[(wid * 2 + j) * 512];         // chunk-frag g = wid*2 + j
    }

    half8 aQ[2];
    aQ[0] = *(const half8*)&Qh[(size_t)(q0 + c) * DKn + p * 8];
    aQ[1] = *(const half8*)&Qh[(size_t)(q0 + c) * DKn + 32 + p * 8];

    half8 ones;
    #pragma unroll
    for (int i = 0; i < 8; ++i) ones[i] = (_Float16)1.0f;

    float4v acc[4];
    float4v accl = (float4v){0.f, 0.f, 0.f, 0.f};
    #pragma unroll
    for (int i = 0; i < 4; ++i)
        acc[i] = (float4v){0.f, 0.f, 0.f, 0.f};

    // stage chunk index t into buffer bo (elems offset).
    // K: contiguous frags at Kh + t*4096; wave w stages source frags (2w+j)
    // V: source frag f = wid*4 + hh2*2 + j -> LDS chunk-frag g = wid*2 + j
    auto stage = [&](int t, int bo) {
        const int kt = t * 64;
        const unsigned short* ks = Kh + (size_t)kt * 64 + lane * 8;
        GLL16(ks + (2 * wid + 0) * 512, lk[0] + bo);
        GLL16(ks + (2 * wid + 1) * 512, lk[1] + bo);
        const int T = kt >> 7, hh2 = (kt >> 6) & 1;
        const unsigned short* vs = Vh + (size_t)T * 8192 + lane * 8;
        GLL16(vs + (wid * 4 + hh2 * 2 + 0) * 512, lv[0] + bo);
        GLL16(vs + (wid * 4 + hh2 * 2 + 1) * 512, lv[1] + bo);
    };

    // prologue: stage chunks 0 and 1 into buffers 0 and 1 (4+4 loads/wave)
    stage(0, 0);
    stage(1, TBE);

    int cur = 0;                        // t % 3
    for (int t = 0; t < NT; ++t) {
        if (t < NT - 1) PIPE_WAIT_BARRIER(4);   // t done, t+1 in flight
        else            PIPE_WAIT_BARRIER(0);
        if (t + 2 < NT) {               // stage chunk t+2 into buf[(t+2)%3]
            int st = cur - 1; if (st < 0) st += 3;   // (t+2)%3 == (t-1)%3
            stage(t + 2, st * TBE);
        }

        const unsigned short* sKc = &sK[cur * TBE];
        const unsigned short* sVc = &sV[cur * TBE];
        const float4v z = {0.f, 0.f, 0.f, 0.f};

        #pragma unroll
        for (int GP = 0; GP < 2; ++GP) {    // 2 groups of 32 keys
            half8 kf0 = *(const half8*)&sKc[(4 * GP + 0) * 512 + lane * 8];
            half8 kf1 = *(const half8*)&sKc[(4 * GP + 1) * 512 + lane * 8];
            half8 kf2 = *(const half8*)&sKc[(4 * GP + 2) * 512 + lane * 8];
            half8 kf3 = *(const half8*)&sKc[(4 * GP + 3) * 512 + lane * 8];
            half8 va[4];
            #pragma unroll
            for (int df = 0; df < 4; ++df)
                va[df] = *(const half8*)&sVc[(df * 2 + GP) * 512 + lane * 8];
            // S^T: lane (p,c) -> q=c, keys t*64 + GP*32 + hi*16 + p*4 + r
            float4v st0 = __builtin_amdgcn_mfma_f32_16x16x32_f16(
                kf0, aQ[0], z, 0, 0, 0);
            st0 = __builtin_amdgcn_mfma_f32_16x16x32_f16(
                kf1, aQ[1], st0, 0, 0, 0);
            float4v st1 = __builtin_amdgcn_mfma_f32_16x16x32_f16(
                kf2, aQ[0], z, 0, 0, 0);
            st1 = __builtin_amdgcn_mfma_f32_16x16x32_f16(
                kf3, aQ[1], st1, 0, 0, 0);
            const float e0 = fexp2(st0[0]), e1 = fexp2(st0[1]);
            const float e2 = fexp2(st0[2]), e3 = fexp2(st0[3]);
            const float e4 = fexp2(st1[0]), e5 = fexp2(st1[1]);
            const float e6 = fexp2(st1[2]), e7 = fexp2(st1[3]);
            // pv8[j]: j = hi*4 + r  (matches kappa ordering)
#if __has_builtin(__builtin_amdgcn_cvt_pkrtz)
            union { fp16x2 h2[4]; half8 v8; } pu;
            pu.h2[0] = __builtin_amdgcn_cvt_pkrtz(e0, e1);
            pu.h2[1] = __builtin_amdgcn_cvt_pkrtz(e2, e3);
            pu.h2[2] = __builtin_amdgcn_cvt_pkrtz(e4, e5);
            pu.h2[3] = __builtin_amdgcn_cvt_pkrtz(e6, e7);
            const half8 pv = pu.v8;
#else
            const half8 pv = { (_Float16)e0, (_Float16)e1, (_Float16)e2,
                               (_Float16)e3, (_Float16)e4, (_Float16)e5,
                               (_Float16)e6, (_Float16)e7 };
#endif
            // row-sum on the MFMA pipe (all D rows identical = denominator)
            accl = __builtin_amdgcn_mfma_f32_16x16x32_f16(ones, pv, accl, 0, 0, 0);
            #pragma unroll
            for (int df = 0; df < 4; ++df)
                acc[df] = __builtin_amdgcn_mfma_f32_16x16x32_f16(
                    va[df], pv, acc[df], 0, 0, 0);
        }
        ++cur; if (cur == 3) cur = 0;
    }

    // epilogue: acc = ctx^T: lane (p,c) holds d = df*16 + p*4 + r at q = c.
    // accl[0] = full softmax denominator for q = c (no shuffle needed).
    // Write ctx in A-frag-major: m = b*2048 + q0 + c, k = h*64 + d.
    {
        const float invl = 1.f / accl[0];
        const int mg = (b * 2048 + q0) >> 4;             // m-group (m&15 = c)
        #pragma unroll
        for (int df = 0; df < 4; ++df) {
            const int kg2 = h * 2 + (df >> 1);
            const int l  = (((df & 1) << 1) + (p >> 1)) * 16 + c;
            half4 hv = { (_Float16)(acc[df][0] * invl),
                         (_Float16)(acc[df][1] * invl),
                         (_Float16)(acc[df][2] * invl),
                         (_Float16)(acc[df][3] * invl) };
            *(half4*)&ctx[((size_t)mg * 32 + kg2) * 512 + l * 8 + (p & 1) * 4] = hv;
        }
    }
}

// ---------------------------------------------------------------------------
extern "C" void kernel_launch(void* const* d_in, const int* in_sizes, int n_in,
                              void* d_out, int out_size, void* d_ws, size_t ws_size,
                              hipStream_t stream)
{
    const float* x  = (const float*)d_in[0];
    const float* Wq = (const float*)d_in[1];
    const float* bq = (const float*)d_in[2];
    const float* Wk = (const float*)d_in[3];
    const float* bk = (const float*)d_in[4];
    const float* Wv = (const float*)d_in[5];
    const float* bv = (const float*)d_in[6];
    const float* Wo = (const float*)d_in[7];
    const float* bo = (const float*)d_in[8];

    _Float16* xh  = (_Float16*)d_ws;                     // 8 MB, A-frag-major
    _Float16* Wt4 = xh + NELT;                           // 8 MB, B-frag-major x4
    unsigned short* Qb = (unsigned short*)(Wt4 + 4 * WELT);  // Q row-major f16
    unsigned short* Kb = Qb + NELT;                      // K attn-frag-major
    unsigned short* Vb = Kb + NELT;                      // V^T frag-major (perm-k)
    _Float16* Ch = (_Float16*)(Vb + NELT);               // ctx A-frag-major

    // fused converters: blocks [0,4096) conv_a, [4096,8192) conv_wt4
    conv_fused<<<8192, 256, 0, stream>>>(x, xh, Wq, Wk, Wv, Wo, Wt4);

    // fused QKV: 128x128 tiles, 24 n-tiles x 32 m-tiles = 768 blocks (3/CU)
    gemm_s<8, 1><<<768, 256, 0, stream>>>(xh, Wt4, bq, bk, bv, (void*)Qb, 24);

    // attention: 64-row q-tiles, KVBLK=64, 3-buffer counted-vmcnt pipeline
    attn_v15<<<1024, 256, 0, stream>>>(Qb, Kb, Vb, Ch);

    // O projection: 64x128 tiles, 8 n-tiles x 64 m-tiles = 512 blocks (2/CU)
    gemm_s<4, 0><<<512, 256, 0, stream>>>(Ch, Wt4 + 3 * WELT, bo, bo, bo,
                                          d_out, 8);
}

// Round 19
// 184.283 us; speedup vs baseline: 1.0583x; 1.0583x over previous
//
#include <hip/hip_runtime.h>
#include <hip/hip_bf16.h>
#include <math.h>

// Problem constants (fixed by the reference)
#define Bn   2
#define Sn   2048
#define En   1024
#define Hn   16
#define DKn  64
#define Mn   (Bn * Sn)   // 4096
#define NELT ((size_t)Mn * En)   // 4,194,304
#define WELT ((size_t)En * En)   // 1,048,576
#define HELT (Sn * DKn)          // 131072 elems per head (K/V frag regions)

// Q pre-scale: 1/sqrt(DK) * log2(e)  -> attention uses exp2 (raw v_exp_f32)
#define QSCALE 0.18033688011112042f

typedef __attribute__((ext_vector_type(8))) short     short8;   // 8x16b
typedef __attribute__((ext_vector_type(8))) _Float16  half8;    // 8 f16
typedef __attribute__((ext_vector_type(4))) _Float16  half4;
typedef __attribute__((ext_vector_type(2))) __fp16    fp16x2;   // cvt_pkrtz ret
typedef __attribute__((ext_vector_type(4))) float     float4v;  // MFMA C/D

static __device__ __forceinline__ unsigned short f2h(float f) {
    _Float16 h = (_Float16)f;
    return *reinterpret_cast<unsigned short*>(&h);
}

static __device__ __forceinline__ float fexp2(float x) {
#if __has_builtin(__builtin_amdgcn_exp2f)
    return __builtin_amdgcn_exp2f(x);
#else
    return exp2f(x);
#endif
}

// A/B-fragment-major offset for a [rows][1024] f16 matrix staged as 16x32
// tiles: off = ((row>>4)*32 + (k>>5))*512 + (((k>>3)&3)*16 + (row&15))*8 + (k&7)
static __device__ __forceinline__ size_t fragoff(int row, int k) {
    return ((size_t)((row >> 4) * 32 + (k >> 5))) * 512
         + (size_t)((((k >> 3) & 3) * 16 + (row & 15)) * 8 + (k & 7));
}

// async global->LDS, 16B/lane; LDS dst = wave-uniform base + lane*16
#define GLL16(gp, lp) __builtin_amdgcn_global_load_lds(                      \
    (const __attribute__((address_space(1))) void*)(gp),                     \
    (__attribute__((address_space(3))) void*)(lp), 16, 0, 0)

// counted vmem wait + raw barrier + sched fence (GEMM pipeline only —
// measured better for gemm_s in R3; measured WORSE for attn in R3 and R18:
// attn's per-wave VALU phase between MFMA clusters makes order-pinned deep
// pipelines serialize issue. attn uses 2-buffer + __syncthreads.)
#define PIPE_WAIT_BARRIER(N)                                                 \
    do {                                                                     \
        asm volatile("s_waitcnt vmcnt(%0)" :: "i"(N) : "memory");            \
        __builtin_amdgcn_s_barrier();                                        \
        __builtin_amdgcn_sched_barrier(0);                                   \
    } while (0)

// ---------------------------------------------------------------------------
// Fused converter: blocks [0,4096) = x fp32 -> f16 A-frag-major;
// blocks [4096,8192) = W^T B-frag-major transpose (one launch, R17).
// ---------------------------------------------------------------------------
__global__ __launch_bounds__(256) void conv_fused(
    const float* __restrict__ in, _Float16* __restrict__ out,
    const float* __restrict__ W0, const float* __restrict__ W1,
    const float* __restrict__ W2, const float* __restrict__ W3,
    _Float16* __restrict__ Wt4)
{
    __shared__ float sT[32][33];
    if (blockIdx.x < 4096) {
        // conv_a path
        const int i = (blockIdx.x * 256 + threadIdx.x) * 4;
        float4 v = *(const float4*)&in[i];
        const int m = i >> 10, k = i & 1023;  // k%4==0 -> half4 stays in octet
        half4 h = { (_Float16)v.x, (_Float16)v.y, (_Float16)v.z, (_Float16)v.w };
        *(half4*)&out[fragoff(m, k)] = h;
    } else {
        // conv_wt4 path
        const int r0 = blockIdx.x - 4096;
        const int z  = r0 >> 10, rem = r0 & 1023;
        const int n0 = (rem & 31) * 32, k0 = (rem >> 5) * 32;
        const float* W = (z == 0) ? W0 : (z == 1) ? W1 : (z == 2) ? W2 : W3;
        _Float16* Wt = Wt4 + (size_t)z * WELT;

        const int t = threadIdx.x;
        #pragma unroll
        for (int it = 0; it < 4; ++it) {
            const int idx = t + 256 * it;
            const int r = idx >> 5, cl = idx & 31;
            sT[r][cl] = W[(size_t)(k0 + r) * En + n0 + cl];
        }
        __syncthreads();
        #pragma unroll
        for (int it = 0; it < 4; ++it) {
            const int idx = t + 256 * it;
            const int r = idx >> 5, cl = idx & 31;
            // element W^T[n0+r][k0+cl]
            Wt[fragoff(n0 + r, k0 + cl)] = (_Float16)sT[cl][r];
        }
    }
}

// ---------------------------------------------------------------------------
// fp16 MFMA GEMM, fragment-major LDS, 3-buffer 2-tile-deep pipeline (R3).
// A and B stored frag-major in global: each GLL16 source is
// base + frag*512 + lane*8 — fully-coalesced 1KB wave read (R8 win).
// Block tile: (MT*16) x 128, 4 waves (2x2), wave = (MT*8) x 64.
// MODE 0: fp32 out[M][1024] (O projection, bias b0)
// MODE 1: fused QKV (Ntot=3072): Q row-major f16 (scaled QSCALE);
//         K attn-frag-major; V^T attn-frag-major with PERMUTED-k layout
//         (lane (p,c) holds its 8 PV keys contiguously -> b128 read and
//          K=32 PV MFMA; permutation kappa(p,j) = (j>>2)*16 + p*4 + (j&3)).
// ---------------------------------------------------------------------------
template<int MT, int MODE>
__global__ __launch_bounds__(256) void gemm_s(
    const _Float16* __restrict__ A, const _Float16* __restrict__ Bt,
    const float* __restrict__ b0, const float* __restrict__ b1,
    const float* __restrict__ b2, void* __restrict__ out, int nT)
{
    constexpr int MH = MT / 2;        // m-frags per wave
    constexpr int NF = MT + 8;        // total frags to stage
    constexpr int NW = NF / 4;        // frags staged per wave (= loads/tile/wave)
    constexpr int BUFE = NF * 512;    // fp16 elems per LDS buffer
    constexpr int NT = En / 32;       // 32 K-tiles

    __shared__ _Float16 sAB[3 * BUFE];

    const int tid  = threadIdx.x;
    const int wid  = tid >> 6, lane = tid & 63;
    const int c    = lane & 15, p = lane >> 4;

    // XCD-aware decode (heuristic: block -> XCD is round-robin by linear id)
    const int lin  = blockIdx.x;
    const int xcd  = lin & 7, slot = lin >> 3;
    const int slab = nT >> 3;                     // n-tiles per XCD
    const int n_t  = xcd * slab + (slot % slab);
    const int m_t  = slot / slab;
    const int m0   = m_t * (MT * 16), n0 = n_t * 128;

    // staging: frag fi in [0,MT) = A-frag, [MT,MT+8) = B-frag; sources are
    // frag-major: (group)*32*512 + t*512 + lane*8, t = K-step index
    const _Float16* gsrc[NW];
    _Float16* ldst[NW];
    #pragma unroll
    for (int j = 0; j < NW; ++j) {
        const int fi = wid * NW + j;
        if (fi < MT) {
            gsrc[j] = A + ((size_t)(m0 / 16 + fi) * 32) * 512 + lane * 8;
        } else {
            const int z = n0 >> 10, nn0 = n0 & 1023;
            gsrc[j] = Bt + (size_t)z * WELT
                    + ((size_t)(nn0 / 16 + (fi - MT)) * 32) * 512 + lane * 8;
        }
        ldst[j] = &sAB[fi * 512];
    }

    const int mf = (wid >> 1) * MH;    // wave's first m-frag
    const int nf = (wid & 1) * 4;      // wave's first n-frag

    float4v acc[MH][4];
    #pragma unroll
    for (int mt = 0; mt < MH; ++mt)
        #pragma unroll
        for (int nt = 0; nt < 4; ++nt)
            acc[mt][nt] = (float4v){0.f, 0.f, 0.f, 0.f};

    auto compute = [&](const _Float16* sb) {
        half8 av[MH], bv[4];
        #pragma unroll
        for (int mt = 0; mt < MH; ++mt)
            av[mt] = *(const half8*)&sb[(mf + mt) * 512 + lane * 8];
        #pragma unroll
        for (int nt = 0; nt < 4; ++nt)
            bv[nt] = *(const half8*)&sb[(MT + nf + nt) * 512 + lane * 8];
        #pragma unroll
        for (int mt = 0; mt < MH; ++mt)
            #pragma unroll
            for (int nt = 0; nt < 4; ++nt)
                acc[mt][nt] = __builtin_amdgcn_mfma_f32_16x16x32_f16(
                    av[mt], bv[nt], acc[mt][nt], 0, 0, 0);
    };

    // prologue: stage tiles 0 and 1 into buffers 0 and 1
    #pragma unroll
    for (int j = 0; j < NW; ++j)
        GLL16(gsrc[j], ldst[j]);
    #pragma unroll
    for (int j = 0; j < NW; ++j)
        GLL16(gsrc[j] + 512, ldst[j] + BUFE);

    int cur = 0;                        // t % 3
    for (int t = 0; t < NT; ++t) {
        if (t < NT - 1) PIPE_WAIT_BARRIER(NW);
        else            PIPE_WAIT_BARRIER(0);
        if (t + 2 < NT) {               // stage tile t+2 into buf[(t+2)%3]
            int st = cur - 1; if (st < 0) st += 3;   // (t+2)%3 == (t-1)%3
            #pragma unroll
            for (int j = 0; j < NW; ++j)
                GLL16(gsrc[j] + (t + 2) * 512, ldst[j] + st * BUFE);
        }
        compute(&sAB[cur * BUFE]);
        ++cur; if (cur == 3) cur = 0;
    }

    // epilogue (C/D: col=c -> n, row=p*4+r -> m)
    #pragma unroll
    for (int mt = 0; mt < MH; ++mt) {
        #pragma unroll
        for (int nt = 0; nt < 4; ++nt) {
            const int n = n0 + (nf + nt) * 16 + c;
            const int mbase = m0 + (mf + mt) * 16 + p * 4;
            if (MODE == 0) {
                const float bia = b0[n];
                float* o = (float*)out;
                #pragma unroll
                for (int r = 0; r < 4; ++r)
                    o[(size_t)(mbase + r) * En + n] = acc[mt][nt][r] + bia;
            } else {
                const int which = n >> 10, nn = n & 1023;
                const int hh = nn >> 6, d = nn & 63;
                const float* bb = (which == 0) ? b0 : (which == 1) ? b1 : b2;
                const float bia = bb[nn];
                unsigned short* o = (unsigned short*)out + (size_t)which * NELT;
                if (which == 0) {          // Q row-major [b,h,s,d], scaled
                    #pragma unroll
                    for (int r = 0; r < 4; ++r) {
                        const int m = mbase + r;
                        const int b = m >> 11, s = m & 2047;
                        o[(((size_t)(b * Hn + hh) * Sn + s) << 6) + d] =
                            f2h((acc[mt][nt][r] + bia) * QSCALE);
                    }
                } else if (which == 1) {   // K attn-frag-major per head
                    #pragma unroll
                    for (int r = 0; r < 4; ++r) {
                        const int m = mbase + r;
                        const int b = m >> 11, s = m & 2047;
                        const int T = s >> 7, sk = s & 127;
                        const int f = ((sk >> 4) << 1) + (d >> 5);
                        const int l = (((d >> 3) & 3) << 4) + (sk & 15);
                        o[(size_t)(b * Hn + hh) * HELT + T * 8192
                          + f * 512 + l * 8 + (d & 7)] =
                            f2h(acc[mt][nt][r] + bia);
                    }
                } else {                   // V^T attn-frag-major, permuted-k
                    const int b = mbase >> 11, sv = mbase & 2047;
                    const int T = sv >> 7, kk = sv & 127;
                    const int kk32 = kk & 31;
                    const int f = ((d >> 4) << 2) + (kk >> 5);
                    // elem = (p*16 + (d&15))*8 + hi*4 + j2; r = j2 (kk%4==0)
                    const int el = ((((kk32 >> 2) & 3) * 16 + (d & 15)) << 3)
                                 + ((kk32 >> 4) << 2);
                    ushort4 pk = make_ushort4(
                        f2h(acc[mt][nt][0] + bia), f2h(acc[mt][nt][1] + bia),
                        f2h(acc[mt][nt][2] + bia), f2h(acc[mt][nt][3] + bia));
                    *(ushort4*)&o[(size_t)(b * Hn + hh) * HELT + T * 8192
                                  + f * 512 + el] = pk;
                }
            }
        }
    }
}

// ---------------------------------------------------------------------------
// MFMA flash attention v14 (R17-passing, measured best 50.8 µs): v10 data
// path at q-tile 64 / KVBLK 64 (4 blocks/CU), 2-buffer issue-early prefetch
// with plain __syncthreads (counted-vmcnt pipelines measured WORSE for attn
// in both R3 and R18), in-register softmax via swapped QK^T + kappa-permuted
// full-rate K=32 PV, ones-MFMA row-sum on the MFMA pipe, cvt_pkrtz P-pack.
// ---------------------------------------------------------------------------
__global__ __launch_bounds__(256) void attn_v14(
    const unsigned short* __restrict__ Q, const unsigned short* __restrict__ K,
    const unsigned short* __restrict__ Vt, _Float16* __restrict__ ctx)
{
    constexpr int TBE = 8 * 512;                  // elems per tile buffer (8 KB)
    __shared__ unsigned short sK[2 * TBE];        // 16 KB
    __shared__ unsigned short sV[2 * TBE];        // 16 KB

    const int tid  = threadIdx.x;
    const int wid  = tid >> 6, lane = tid & 63;
    const int c    = lane & 15, p = lane >> 4;

    const int lin  = blockIdx.x;                  // 0..1023
    const int xcd  = lin & 7, slot = lin >> 3;    // slot 0..127
    const int he   = xcd * 4 + (slot & 3);        // 0..31
    const int qt   = slot >> 2;                   // 0..31 (64-row q-tile)
    const int b    = he >> 4, h = he & 15;
    const int q0   = qt * 64 + wid * 16;          // 16 q-rows per wave
    const size_t hb = (size_t)(b * Hn + h);

    const unsigned short* Qh = Q  + hb * Sn * DKn;   // row-major
    const unsigned short* Kh = K  + hb * HELT;       // frag-major tiles
    const unsigned short* Vh = Vt + hb * HELT;       // frag-major (permuted-k)

    // K: chunk is linear at Kh + kt*64; wave stages chunk-frags {2w,2w+1}
    unsigned short* lk[2];
    unsigned short* lv[2];
    #pragma unroll
    for (int j = 0; j < 2; ++j) {
        lk[j] = &sK[(2 * wid + j) * 512];
        lv[j] = &sV[(wid * 2 + j) * 512];         // chunk-frag g = wid*2 + j
    }

    half8 aQ[2];
    aQ[0] = *(const half8*)&Qh[(size_t)(q0 + c) * DKn + p * 8];
    aQ[1] = *(const half8*)&Qh[(size_t)(q0 + c) * DKn + 32 + p * 8];

    half8 ones;
    #pragma unroll
    for (int i = 0; i < 8; ++i) ones[i] = (_Float16)1.0f;

    float4v acc[4];
    float4v accl = (float4v){0.f, 0.f, 0.f, 0.f};
    #pragma unroll
    for (int i = 0; i < 4; ++i)
        acc[i] = (float4v){0.f, 0.f, 0.f, 0.f};

    // stage chunk kt into buffer bo.
    // K: contiguous frags at Kh + kt*64; wave w stages source frags (2w+j)
    // V: source frag f = wid*4 + hh2*2 + j -> LDS chunk-frag g = wid*2 + j
    auto stage = [&](int kt, int bo) {
        const unsigned short* ks = Kh + (size_t)kt * 64 + lane * 8;
        GLL16(ks + (2 * wid + 0) * 512, lk[0] + bo);
        GLL16(ks + (2 * wid + 1) * 512, lk[1] + bo);
        const int T = kt >> 7, hh2 = (kt >> 6) & 1;
        const unsigned short* vs = Vh + (size_t)T * 8192 + lane * 8;
        GLL16(vs + (wid * 4 + hh2 * 2 + 0) * 512, lv[0] + bo);
        GLL16(vs + (wid * 4 + hh2 * 2 + 1) * 512, lv[1] + bo);
    };

    // prologue: stage chunk 0 into buffer 0
    stage(0, 0);
    __syncthreads();

    int cur = 0;
    for (int kt = 0; kt < Sn; kt += 64) {
        if (kt + 64 < Sn)                   // prefetch next chunk (issue-early)
            stage(kt + 64, (cur ^ 1) * TBE);

        const unsigned short* sKc = &sK[cur * TBE];
        const unsigned short* sVc = &sV[cur * TBE];
        const float4v z = {0.f, 0.f, 0.f, 0.f};

        #pragma unroll
        for (int GP = 0; GP < 2; ++GP) {    // 2 groups of 32 keys
            half8 kf0 = *(const half8*)&sKc[(4 * GP + 0) * 512 + lane * 8];
            half8 kf1 = *(const half8*)&sKc[(4 * GP + 1) * 512 + lane * 8];
            half8 kf2 = *(const half8*)&sKc[(4 * GP + 2) * 512 + lane * 8];
            half8 kf3 = *(const half8*)&sKc[(4 * GP + 3) * 512 + lane * 8];
            half8 va[4];
            #pragma unroll
            for (int df = 0; df < 4; ++df)
                va[df] = *(const half8*)&sVc[(df * 2 + GP) * 512 + lane * 8];
            // S^T: lane (p,c) -> q=c, keys kt + GP*32 + hi*16 + p*4 + r
            float4v st0 = __builtin_amdgcn_mfma_f32_16x16x32_f16(
                kf0, aQ[0], z, 0, 0, 0);
            st0 = __builtin_amdgcn_mfma_f32_16x16x32_f16(
                kf1, aQ[1], st0, 0, 0, 0);
            float4v st1 = __builtin_amdgcn_mfma_f32_16x16x32_f16(
                kf2, aQ[0], z, 0, 0, 0);
            st1 = __builtin_amdgcn_mfma_f32_16x16x32_f16(
                kf3, aQ[1], st1, 0, 0, 0);
            const float e0 = fexp2(st0[0]), e1 = fexp2(st0[1]);
            const float e2 = fexp2(st0[2]), e3 = fexp2(st0[3]);
            const float e4 = fexp2(st1[0]), e5 = fexp2(st1[1]);
            const float e6 = fexp2(st1[2]), e7 = fexp2(st1[3]);
            // pv8[j]: j = hi*4 + r  (matches kappa ordering)
#if __has_builtin(__builtin_amdgcn_cvt_pkrtz)
            union { fp16x2 h2[4]; half8 v8; } pu;
            pu.h2[0] = __builtin_amdgcn_cvt_pkrtz(e0, e1);
            pu.h2[1] = __builtin_amdgcn_cvt_pkrtz(e2, e3);
            pu.h2[2] = __builtin_amdgcn_cvt_pkrtz(e4, e5);
            pu.h2[3] = __builtin_amdgcn_cvt_pkrtz(e6, e7);
            const half8 pv = pu.v8;
#else
            const half8 pv = { (_Float16)e0, (_Float16)e1, (_Float16)e2,
                               (_Float16)e3, (_Float16)e4, (_Float16)e5,
                               (_Float16)e6, (_Float16)e7 };
#endif
            // row-sum on the MFMA pipe: D[row][c] = sum_k P[k][c] (all rows
            // identical; cross-lane sum done by the MFMA's K-reduction)
            accl = __builtin_amdgcn_mfma_f32_16x16x32_f16(ones, pv, accl, 0, 0, 0);
            #pragma unroll
            for (int df = 0; df < 4; ++df)
                acc[df] = __builtin_amdgcn_mfma_f32_16x16x32_f16(
                    va[df], pv, acc[df], 0, 0, 0);
        }
        __syncthreads();                    // vmcnt drain + LDS reuse fence
        cur ^= 1;
    }

    // epilogue: acc = ctx^T: lane (p,c) holds d = df*16 + p*4 + r at q = c.
    // accl[0] = full softmax denominator for q = c (no shuffle needed).
    // Write ctx in A-frag-major: m = b*2048 + q0 + c, k = h*64 + d.
    {
        const float invl = 1.f / accl[0];
        const int mg = (b * 2048 + q0) >> 4;             // m-group (m&15 = c)
        #pragma unroll
        for (int df = 0; df < 4; ++df) {
            const int kg2 = h * 2 + (df >> 1);
            const int l  = (((df & 1) << 1) + (p >> 1)) * 16 + c;
            half4 hv = { (_Float16)(acc[df][0] * invl),
                         (_Float16)(acc[df][1] * invl),
                         (_Float16)(acc[df][2] * invl),
                         (_Float16)(acc[df][3] * invl) };
            *(half4*)&ctx[((size_t)mg * 32 + kg2) * 512 + l * 8 + (p & 1) * 4] = hv;
        }
    }
}

// ---------------------------------------------------------------------------
extern "C" void kernel_launch(void* const* d_in, const int* in_sizes, int n_in,
                              void* d_out, int out_size, void* d_ws, size_t ws_size,
                              hipStream_t stream)
{
    const float* x  = (const float*)d_in[0];
    const float* Wq = (const float*)d_in[1];
    const float* bq = (const float*)d_in[2];
    const float* Wk = (const float*)d_in[3];
    const float* bk = (const float*)d_in[4];
    const float* Wv = (const float*)d_in[5];
    const float* bv = (const float*)d_in[6];
    const float* Wo = (const float*)d_in[7];
    const float* bo = (const float*)d_in[8];

    _Float16* xh  = (_Float16*)d_ws;                     // 8 MB, A-frag-major
    _Float16* Wt4 = xh + NELT;                           // 8 MB, B-frag-major x4
    unsigned short* Qb = (unsigned short*)(Wt4 + 4 * WELT);  // Q row-major f16
    unsigned short* Kb = Qb + NELT;                      // K attn-frag-major
    unsigned short* Vb = Kb + NELT;                      // V^T frag-major (perm-k)
    _Float16* Ch = (_Float16*)(Vb + NELT);               // ctx A-frag-major

    // fused converters: blocks [0,4096) conv_a, [4096,8192) conv_wt4
    conv_fused<<<8192, 256, 0, stream>>>(x, xh, Wq, Wk, Wv, Wo, Wt4);

    // fused QKV: 128x128 tiles, 24 n-tiles x 32 m-tiles = 768 blocks (3/CU)
    gemm_s<8, 1><<<768, 256, 0, stream>>>(xh, Wt4, bq, bk, bv, (void*)Qb, 24);

    // attention: 64-row q-tiles, KVBLK=64 -> 1024 blocks (4/CU, 4 waves/SIMD)
    attn_v14<<<1024, 256, 0, stream>>>(Qb, Kb, Vb, Ch);

    // O projection: 64x128 tiles, 8 n-tiles x 64 m-tiles = 512 blocks (2/CU)
    gemm_s<4, 0><<<512, 256, 0, stream>>>(Ch, Wt4 + 3 * WELT, bo, bo, bo,
                                          d_out, 8);
}